// Round 10
// baseline (6840.794 us; speedup 1.0000x reference)
//
#include <hip/hip_runtime.h>
#include <math.h>

#define NN 512
#define BB 32
#define TT 12
#define HH 12
#define UU 64
#define CAP 128
#define RTOT (NN * BB)          // 16384 rows

__device__ __forceinline__ float sigm(float x) { return 1.f / (1.f + expf(-x)); }

// ---------------- ELL build: int2 {idx, val_bits} at [p*1024 + s*512 + row] -----
__global__ __launch_bounds__(256) void build_ell(const float* __restrict__ sup,
                                                 int2* __restrict__ ell,
                                                 int* __restrict__ ecnt) {
    int wave = (blockIdx.x * blockDim.x + threadIdx.x) >> 6;
    int lane = threadIdx.x & 63;
    if (wave >= 2 * NN) return;
    const float* row = sup + (size_t)wave * NN;
    int base = 0;
    for (int k = 0; k < NN / 64; ++k) {
        float v = row[k * 64 + lane];
        unsigned long long m = __ballot(v != 0.0f);
        int pre = __popcll(m & ((1ull << lane) - 1ull));
        if (v != 0.0f) {
            int pos = base + pre;
            if (pos < CAP)
                ell[(size_t)pos * 1024 + wave] = make_int2(k * 64 + lane, __float_as_int(v));
        }
        base += __popcll(m);
    }
    if (lane == 0) ecnt[wave] = base < CAP ? base : CAP;
}

__global__ void zero_kernel(float* __restrict__ p, int n) {
    int i = blockIdx.x * 256 + threadIdx.x;
    if (i < n) p[i] = 0.0f;
}

// ---------------- weight pre-subtraction: Wmod row m=0 := W0 - W2 - W4 ----------
__global__ void wsub(const float* __restrict__ src, float* __restrict__ dst,
                     int C, int OO) {
    int idx = blockIdx.x * 256 + threadIdx.x;
    if (idx >= C * OO) return;
    int c = idx / OO, o = idx - c * OO;
    size_t base = (size_t)c * 5 * OO + o;
    float w0 = src[base], w2 = src[base + 2 * OO], w4 = src[base + 4 * OO];
    dst[base] = w0 - w2 - w4;
    dst[base + 1 * OO] = src[base + 1 * OO];
    dst[base + 2 * OO] = w2;
    dst[base + 3 * OO] = src[base + 3 * OO];
    dst[base + 4 * OO] = w4;
}

// ---------------- dense GEMM: Zm = X0_h @ Wm (h-channels only; x via combine) ---
// 128n x 64o tile, 256 threads (thread = 8n x 4o); LDS-transpose epilogue to
// 4-wide o-blocked Z: Z[m][b][ogZ][512n][4oi]   (gate: 32 ogZ, cand: 16 ogZ)
template<bool L0, bool GATED, int OO>
__global__ __launch_bounds__(256) void gemm_f(const float* __restrict__ hA,
                                              const float* __restrict__ hB,
                                              const float* __restrict__ g,
                                              const float* __restrict__ W,
                                              float* __restrict__ Z) {
    constexpr int C  = L0 ? 64 : 128;
    constexpr int KT = C / 32;

    __shared__ float At[33][128];   // 16.9 KB (also epilogue scratch, 8*516 fits)
    __shared__ float Ws[32][68];    // 8.7 KB

    int bx = blockIdx.x;
    int b  = bx >> 2;
    int n0 = (bx & 3) * 128;
    int m  = blockIdx.y;
    int ot = blockIdx.z;                 // o-tile (gate: 0/1, cand: 0)
    int tid = threadIdx.x, tx = tid & 15, ty = tid >> 4;

    float acc[8][4];
    #pragma unroll
    for (int i = 0; i < 8; ++i)
        #pragma unroll
        for (int j = 0; j < 4; ++j) acc[i][j] = 0.f;

    float4 va[4], vw[2];

    auto loadAB = [&](int kt) {
        #pragma unroll
        for (int i = 0; i < 4; ++i) {
            int f4 = i * 256 + tid;
            int c = kt * 32 + (f4 >> 5);
            int nn = n0 + (f4 & 31) * 4;
            float4 v;
            if (L0) {
                v = *(const float4*)&hA[(size_t)((b << 6) + c) * 512 + nn];
                if (GATED) {
                    float4 gv = *(const float4*)&g[(size_t)((b << 7) + c) * 512 + nn];
                    v.x *= gv.x; v.y *= gv.y; v.z *= gv.z; v.w *= gv.w;
                }
            } else {
                if (c < 64) {
                    v = *(const float4*)&hA[(size_t)((b << 6) + c) * 512 + nn];
                } else {
                    int u = c - 64;
                    v = *(const float4*)&hB[(size_t)((b << 6) + u) * 512 + nn];
                    if (GATED) {
                        float4 gv = *(const float4*)&g[(size_t)((b << 7) + u) * 512 + nn];
                        v.x *= gv.x; v.y *= gv.y; v.z *= gv.z; v.w *= gv.w;
                    }
                }
            }
            va[i] = v;
        }
        #pragma unroll
        for (int i = 0; i < 2; ++i) {
            int f4 = i * 256 + tid;
            int kk = f4 >> 4, o4 = f4 & 15;
            int c = kt * 32 + kk;
            int crow = L0 ? (c + 1) : c;      // L0: x occupies original row 0
            vw[i] = *(const float4*)&W[(size_t)(crow * 5 + m) * OO + ot * 64 + o4 * 4];
        }
    };
    auto stash = [&]() {
        #pragma unroll
        for (int i = 0; i < 4; ++i) {
            int f4 = i * 256 + tid;
            *(float4*)&At[f4 >> 5][(f4 & 31) * 4] = va[i];
        }
        #pragma unroll
        for (int i = 0; i < 2; ++i) {
            int f4 = i * 256 + tid;
            *(float4*)&Ws[f4 >> 4][(f4 & 15) * 4] = vw[i];
        }
    };

    loadAB(0);
    for (int kt = 0; kt < KT; ++kt) {
        __syncthreads();
        stash();
        __syncthreads();
        if (kt + 1 < KT) loadAB(kt + 1);
        #pragma unroll 8
        for (int kk = 0; kk < 32; ++kk) {
            float4 a0 = *(float4*)&At[kk][ty * 8];
            float4 a1 = *(float4*)&At[kk][ty * 8 + 4];
            float4 w  = *(float4*)&Ws[kk][tx * 4];
            float av[8] = {a0.x, a0.y, a0.z, a0.w, a1.x, a1.y, a1.z, a1.w};
            #pragma unroll
            for (int i = 0; i < 8; ++i) {
                acc[i][0] += av[i] * w.x; acc[i][1] += av[i] * w.y;
                acc[i][2] += av[i] * w.z; acc[i][3] += av[i] * w.w;
            }
        }
    }
    __syncthreads();

    // 4-wide transpose epilogue (both OO): ogZ count = OO/4
    float* lds = &At[0][0];
    float* ZmB = Z + (size_t)(m * 32 + b) * ((OO / 4) * 2048);
    #pragma unroll
    for (int p = 0; p < 2; ++p) {
        if ((tx >> 3) == p) {
            int a = tx & 7;
            #pragma unroll
            for (int i = 0; i < 8; ++i)
                *(float4*)&lds[a * 516 + (ty * 8 + i) * 4] =
                    make_float4(acc[i][0], acc[i][1], acc[i][2], acc[i][3]);
        }
        __syncthreads();
        #pragma unroll
        for (int j = 0; j < 4; ++j) {
            int a = j * 2 + (tid >> 7);
            int q4 = tid & 127;
            float4 v = *(float4*)&lds[a * 516 + q4 * 4];
            int ogZ = ot * 16 + p * 8 + a;
            *(float4*)&ZmB[(size_t)ogZ * 2048 + n0 * 4 + q4 * 4] = v;
        }
        __syncthreads();
    }
}

// ---------------- combine: out = Z024 + S1(Z1+2S1Z2) + S2(Z3+2S2Z4) -------------
// Z slot 0 holds Z024 = X@(W0-W2-W4) via Wmod. 4 o's per block, 3 barriers.
// HX: add x[b][n] * Wmod[row0, m] at read/stage time.
// MODE 0: gate -> g = sigmoid(out + bg)        (OO=128, grid 1024)
// MODE 1: cand -> h = u*h + (1-u)*tanh(out+bc) (OO=64,  grid 512), u from gin
template<int MODE, bool HX>
__global__ __launch_bounds__(512) void combine(const float* __restrict__ Z,
                                               const int2* __restrict__ ell,
                                               const int* __restrict__ ecnt,
                                               const float* __restrict__ bias,
                                               const float* __restrict__ xv,
                                               const float* __restrict__ Wx,
                                               float* __restrict__ gout,
                                               const float* __restrict__ gin,
                                               float* __restrict__ h) {
    constexpr int OO = (MODE == 0) ? 128 : 64;
    constexpr int OQ = OO / 4;
    const size_t MS = (size_t)RTOT * OO;

    __shared__ float Ta[512 * 4];
    __shared__ float Tb[512 * 4];
    __shared__ float Tc[512 * 4];

    int b  = blockIdx.x / OQ;
    int o0 = (blockIdx.x % OQ) * 4;
    int n  = threadIdx.x;
    const float* Zt = Z + ((size_t)b * OQ + (o0 >> 2)) * 2048;

    int cnt0 = ecnt[n], cnt1 = ecnt[NN + n];
    float xn = HX ? xv[b * 512 + n] : 0.f;

    auto xwv = [&](int m, int fi) -> float {
        return Wx[(size_t)m * OO + o0 + fi];
    };

    float4 s2 = *(const float4*)(Zt + 2 * MS + (size_t)n * 4);
    float4 s4 = *(const float4*)(Zt + 4 * MS + (size_t)n * 4);

    float y1[4], y2[4], z0own[4], g2[4], g4[4], t1[4];
    auto own_ld = [&](int m, float* o) {
        *(float4*)&o[0] = *(const float4*)(Zt + m * MS + (size_t)n * 4);
        if (HX) {
            #pragma unroll
            for (int fi = 0; fi < 4; ++fi) o[fi] += xn * xwv(m, fi);
        }
    };
    own_ld(1, y1);      // Z1 (+hx)
    own_ld(3, y2);      // Z3 (+hx)
    own_ld(0, z0own);   // Z024 (+hx via Wmod row0 m=0)

    float uval[4], hval[4];
    if (MODE == 1) {
        #pragma unroll
        for (int fi = 0; fi < 4; ++fi) {
            uval[fi] = gin[(size_t)((b << 7) + 64 + o0 + fi) * 512 + n];
            hval[fi] = h[(size_t)((b << 6) + o0 + fi) * 512 + n];
        }
    }

    if (HX) {
        s2.x += xn * xwv(2, 0); s2.y += xn * xwv(2, 1);
        s2.z += xn * xwv(2, 2); s2.w += xn * xwv(2, 3);
        s4.x += xn * xwv(4, 0); s4.y += xn * xwv(4, 1);
        s4.z += xn * xwv(4, 2); s4.w += xn * xwv(4, 3);
    }
    *(float4*)&Ta[n * 4] = s2;
    *(float4*)&Tc[n * 4] = s4;

    auto gather = [&](const float* T, int s, float* o) {
        int cnt = s ? cnt1 : cnt0;
        const int2* e0 = ell + s * NN + n;
        float4 a0 = make_float4(0.f, 0.f, 0.f, 0.f);
        for (int p = 0; p < cnt; ++p) {
            int2 e = e0[(size_t)p << 10];
            int j = e.x;
            float v = __int_as_float(e.y);
            float4 x0 = *(const float4*)&T[j * 4];
            a0.x += v * x0.x; a0.y += v * x0.y; a0.z += v * x0.z; a0.w += v * x0.w;
        }
        *(float4*)&o[0] = a0;
    };

    __syncthreads();                    // bar 1: Ta/Tc staged

    gather(Ta, 0, t1);                  // S1 Z2
    #pragma unroll
    for (int fi = 0; fi < 4; ++fi) y1[fi] += 2.f * t1[fi];
    gather(Tc, 1, t1);                  // S2 Z4
    #pragma unroll
    for (int fi = 0; fi < 4; ++fi) y2[fi] += 2.f * t1[fi];

    __syncthreads();                    // bar 2: hop-1 reads done

    *(float4*)&Tb[n * 4] = *(float4*)&y1[0];
    *(float4*)&Tc[n * 4] = *(float4*)&y2[0];

    __syncthreads();                    // bar 3: y tiles ready

    gather(Tb, 0, g2);                  // S1 (Z1 + 2 S1 Z2)
    gather(Tc, 1, g4);                  // S2 (Z3 + 2 S2 Z4)

    #pragma unroll
    for (int fi = 0; fi < 4; ++fi) {
        float acc = z0own[fi] + g2[fi] + g4[fi] + bias[o0 + fi];
        if (MODE == 0) {
            gout[(size_t)((b << 7) + o0 + fi) * 512 + n] = sigm(acc);
        } else {
            float cv = tanhf(acc);
            h[(size_t)((b << 6) + o0 + fi) * 512 + n] =
                uval[fi] * hval[fi] + (1.f - uval[fi]) * cv;
        }
    }
}

// ---------------- projection ----------------------------------------------------
__global__ void proj_kernel(const float* __restrict__ h1, const float* __restrict__ pW,
                            const float* __restrict__ pb, float* __restrict__ outt) {
    int r = blockIdx.x * 256 + threadIdx.x;
    if (r >= RTOT) return;
    int b = r >> 9, n = r & 511;
    float acc = pb[0];
    #pragma unroll 16
    for (int u = 0; u < 64; ++u)
        acc += h1[(size_t)((b << 6) + u) * 512 + n] * pW[u];
    outt[b * NN + n] = acc;
}

// ================================================================================
extern "C" void kernel_launch(void* const* d_in, const int* in_sizes, int n_in,
                              void* d_out, int out_size, void* d_ws, size_t ws_size,
                              hipStream_t stream) {
    const float* inputs   = (const float*)d_in[0];
    const float* supports = (const float*)d_in[1];
    const float* enc0_Wg = (const float*)d_in[2];
    const float* enc0_bg = (const float*)d_in[3];
    const float* enc0_Wc = (const float*)d_in[4];
    const float* enc0_bc = (const float*)d_in[5];
    const float* enc1_Wg = (const float*)d_in[6];
    const float* enc1_bg = (const float*)d_in[7];
    const float* enc1_Wc = (const float*)d_in[8];
    const float* enc1_bc = (const float*)d_in[9];
    const float* dec0_Wg = (const float*)d_in[10];
    const float* dec0_bg = (const float*)d_in[11];
    const float* dec0_Wc = (const float*)d_in[12];
    const float* dec0_bc = (const float*)d_in[13];
    const float* dec1_Wg = (const float*)d_in[14];
    const float* dec1_bg = (const float*)d_in[15];
    const float* dec1_Wc = (const float*)d_in[16];
    const float* dec1_bc = (const float*)d_in[17];
    const float* projW   = (const float*)d_in[18];
    const float* projb   = (const float*)d_in[19];
    float* out = (float*)d_out;

    char* wsb = (char*)d_ws;
    size_t off = 0;
    auto alloc = [&](size_t bytes) -> char* {
        char* p = wsb + off;
        off = (off + bytes + 255) & ~(size_t)255;
        return p;
    };
    int2*  ell   = (int2*)alloc((size_t)CAP * 1024 * 8);
    int*   ecnt  = (int*)alloc((size_t)2 * NN * 4);
    float* h0    = (float*)alloc((size_t)RTOT * UU * 4);     // [b][u][n]
    float* h1    = (float*)alloc((size_t)RTOT * UU * 4);
    float* xzero = (float*)alloc((size_t)RTOT * 4);
    float* g     = (float*)alloc((size_t)RTOT * 128 * 4);    // [b][go][n]
    float* Z     = (float*)alloc((size_t)5 * RTOT * 128 * 4);
    float* m_e0g = (float*)alloc((size_t)65 * 5 * 128 * 4);
    float* m_e0c = (float*)alloc((size_t)65 * 5 * 64 * 4);
    float* m_e1g = (float*)alloc((size_t)128 * 5 * 128 * 4);
    float* m_e1c = (float*)alloc((size_t)128 * 5 * 64 * 4);
    float* m_d0g = (float*)alloc((size_t)65 * 5 * 128 * 4);
    float* m_d0c = (float*)alloc((size_t)65 * 5 * 64 * 4);
    float* m_d1g = (float*)alloc((size_t)128 * 5 * 128 * 4);
    float* m_d1c = (float*)alloc((size_t)128 * 5 * 64 * 4);
    if (off > ws_size) return;

    build_ell<<<256, 256, 0, stream>>>(supports, ell, ecnt);
    {
        int nz = RTOT * UU * 2 + RTOT;  // h0, h1, xzero contiguous
        zero_kernel<<<(nz + 255) / 256, 256, 0, stream>>>(h0, nz);
    }
    wsub<<<(65 * 128 + 255) / 256, 256, 0, stream>>>(enc0_Wg, m_e0g, 65, 128);
    wsub<<<(65 * 64 + 255) / 256, 256, 0, stream>>>(enc0_Wc, m_e0c, 65, 64);
    wsub<<<(128 * 128 + 255) / 256, 256, 0, stream>>>(enc1_Wg, m_e1g, 128, 128);
    wsub<<<(128 * 64 + 255) / 256, 256, 0, stream>>>(enc1_Wc, m_e1c, 128, 64);
    wsub<<<(65 * 128 + 255) / 256, 256, 0, stream>>>(dec0_Wg, m_d0g, 65, 128);
    wsub<<<(65 * 64 + 255) / 256, 256, 0, stream>>>(dec0_Wc, m_d0c, 65, 64);
    wsub<<<(128 * 128 + 255) / 256, 256, 0, stream>>>(dec1_Wg, m_d1g, 128, 128);
    wsub<<<(128 * 64 + 255) / 256, 256, 0, stream>>>(dec1_Wc, m_d1c, 128, 64);

    auto cell_l0 = [&](const float* x_bn, float* h, const float* Wg_, const float* bgp,
                       const float* Wc_, const float* bcp) {
        gemm_f<true, false, 128><<<dim3(128, 5, 2), 256, 0, stream>>>(h, nullptr, nullptr, Wg_, Z);
        combine<0, true><<<1024, 512, 0, stream>>>(Z, ell, ecnt, bgp, x_bn, Wg_,
                                                   g, nullptr, nullptr);
        gemm_f<true, true, 64><<<dim3(128, 5, 1), 256, 0, stream>>>(h, nullptr, g, Wc_, Z);
        combine<1, true><<<512, 512, 0, stream>>>(Z, ell, ecnt, bcp, x_bn, Wc_,
                                                  nullptr, g, h);
    };
    auto cell_l1 = [&](const float* hin, float* h, const float* Wg_, const float* bgp,
                       const float* Wc_, const float* bcp) {
        gemm_f<false, false, 128><<<dim3(128, 5, 2), 256, 0, stream>>>(hin, h, nullptr, Wg_, Z);
        combine<0, false><<<1024, 512, 0, stream>>>(Z, ell, ecnt, bgp, nullptr, nullptr,
                                                    g, nullptr, nullptr);
        gemm_f<false, true, 64><<<dim3(128, 5, 1), 256, 0, stream>>>(hin, h, g, Wc_, Z);
        combine<1, false><<<512, 512, 0, stream>>>(Z, ell, ecnt, bcp, nullptr, nullptr,
                                                   nullptr, g, h);
    };

    for (int t = 0; t < TT; ++t) {
        cell_l0(inputs + (size_t)t * BB * NN, h0, m_e0g, enc0_bg, m_e0c, enc0_bc);
        cell_l1(h0, h1, m_e1g, enc1_bg, m_e1c, enc1_bc);
    }
    for (int t = 0; t < HH; ++t) {
        const float* xin = (t == 0) ? xzero : (out + (size_t)(t - 1) * BB * NN);
        cell_l0(xin, h0, m_d0g, dec0_bg, m_d0c, dec0_bc);
        cell_l1(h0, h1, m_d1g, dec1_bg, m_d1c, dec1_bc);
        proj_kernel<<<(RTOT + 255) / 256, 256, 0, stream>>>(h1, projW, projb,
                                                            out + (size_t)t * BB * NN);
    }
}

// Round 11
// 5615.423 us; speedup vs baseline: 1.2182x; 1.2182x over previous
//
#include <hip/hip_runtime.h>
#include <math.h>

#define NN 512
#define BB 32
#define TT 12
#define HH 12
#define UU 64
#define CAP 128
#define RTOT (NN * BB)          // 16384 rows

__device__ __forceinline__ float sigm(float x) { return 1.f / (1.f + expf(-x)); }

// ---------------- ELL build: int2 {idx, val_bits} at [p*1024 + s*512 + row] -----
__global__ __launch_bounds__(256) void build_ell(const float* __restrict__ sup,
                                                 int2* __restrict__ ell,
                                                 int* __restrict__ ecnt) {
    int wave = (blockIdx.x * blockDim.x + threadIdx.x) >> 6;
    int lane = threadIdx.x & 63;
    if (wave >= 2 * NN) return;
    const float* row = sup + (size_t)wave * NN;
    int base = 0;
    for (int k = 0; k < NN / 64; ++k) {
        float v = row[k * 64 + lane];
        unsigned long long m = __ballot(v != 0.0f);
        int pre = __popcll(m & ((1ull << lane) - 1ull));
        if (v != 0.0f) {
            int pos = base + pre;
            if (pos < CAP)
                ell[(size_t)pos * 1024 + wave] = make_int2(k * 64 + lane, __float_as_int(v));
        }
        base += __popcll(m);
    }
    if (lane == 0) ecnt[wave] = base < CAP ? base : CAP;
}

__global__ void zero_kernel(float* __restrict__ p, int n) {
    int i = blockIdx.x * 256 + threadIdx.x;
    if (i < n) p[i] = 0.0f;
}

// ---------------- weight pre-subtraction: Wmod row m=0 := W0 - W2 - W4 ----------
__global__ void wsub(const float* __restrict__ src, float* __restrict__ dst,
                     int C, int OO) {
    int idx = blockIdx.x * 256 + threadIdx.x;
    if (idx >= C * OO) return;
    int c = idx / OO, o = idx - c * OO;
    size_t base = (size_t)c * 5 * OO + o;
    float w0 = src[base], w2 = src[base + 2 * OO], w4 = src[base + 4 * OO];
    dst[base] = w0 - w2 - w4;
    dst[base + 1 * OO] = src[base + 1 * OO];
    dst[base + 2 * OO] = w2;
    dst[base + 3 * OO] = src[base + 3 * OO];
    dst[base + 4 * OO] = w4;
}

// ---------------- fused gconv: GEMM-in-registers + Chebyshev combine ------------
// Block = (b, o-slice of WD outputs). Phase 1: acc[m][oi] = sum_c A[c][n]*Wm[c][o]
// (A read coalesced from h buffers, W broadcast from LDS). Phase 2: stage acc[2]
// (Z2) and acc[4] (Z4) in LDS tiles, 4 sparse gathers (2 supports x 2 hops),
// out = Z024 + S1(Z1+2S1Z2) + S2(Z3+2S2Z4) + bias. Z never touches HBM.
// GATE: out -> g = sigmoid(.)  (WD=8). else: h_new = u*h_old + (1-u)*tanh(.) (WD=4).
// L0: C=64 (x folded out); rank-1 x-term added from Wmod row 0 post-GEMM.
template<bool L0, bool GATE>
__global__ __launch_bounds__(512) void fused(const float* __restrict__ hA,
                                             const float* __restrict__ hB,
                                             const float* __restrict__ g,
                                             const float* __restrict__ W,
                                             const float* __restrict__ xv,
                                             const float* __restrict__ bias,
                                             const int2* __restrict__ ell,
                                             const int* __restrict__ ecnt,
                                             float* __restrict__ gout,
                                             const float* __restrict__ hOld,
                                             float* __restrict__ hNew) {
    constexpr int C  = L0 ? 64 : 128;
    constexpr int WD = GATE ? 8 : 4;
    constexpr int OO = GATE ? 128 : 64;

    __shared__ float S[512 * WD * 3];       // gate 48KB, cand 24KB
    float* Wt = S;                          // aliases Ta/Tb (dead after phase 1)
    float* Ta = S;
    float* Tb = S + 512 * WD;
    float* Tc = S + 1024 * WD;

    int bid = blockIdx.x;
    int swz = (bid & 7) * 64 + (bid >> 3);  // XCD-contiguous (512 blocks, %8==0)
    int b = swz >> 4, oq = swz & 15;
    int o0 = oq * WD;
    int n = threadIdx.x;
    int cnt0 = ecnt[n], cnt1 = ecnt[NN + n];
    float xn = L0 ? xv[b * 512 + n] : 0.f;

    // ---- stage W tile: Wt[(m*C+c)*WD+oi] ----
    constexpr int TOT = 5 * C * WD;
    constexpr int CW = C * WD;
    for (int e = n; e < TOT; e += 512) {
        int m = e / CW;
        int rem = e % CW;
        int c = rem / WD;
        int oi = rem % WD;
        int crow = L0 ? (c + 1) : c;
        Wt[e] = W[(size_t)(crow * 5 + m) * OO + o0 + oi];
    }
    __syncthreads();

    // ---- phase 1: GEMM in registers ----
    float acc[5][WD];
    #pragma unroll
    for (int m = 0; m < 5; ++m)
        #pragma unroll
        for (int oi = 0; oi < WD; ++oi) acc[m][oi] = 0.f;

    #pragma unroll 2
    for (int c = 0; c < C; ++c) {
        float a;
        if (L0) {
            a = hA[(size_t)((b << 6) + c) * 512 + n];
            if (!GATE) a *= g[(size_t)((b << 7) + c) * 512 + n];
        } else {
            if (c < 64) {
                a = hA[(size_t)((b << 6) + c) * 512 + n];
            } else {
                int u = c - 64;
                a = hB[(size_t)((b << 6) + u) * 512 + n];
                if (!GATE) a *= g[(size_t)((b << 7) + u) * 512 + n];
            }
        }
        #pragma unroll
        for (int m = 0; m < 5; ++m)
            #pragma unroll
            for (int oi = 0; oi < WD; ++oi)
                acc[m][oi] += a * Wt[(m * C + c) * WD + oi];
    }

    // rank-1 x-term (L0): Wmod row 0 (m=0 slot holds W0-W2-W4)
    if (L0) {
        #pragma unroll
        for (int m = 0; m < 5; ++m)
            #pragma unroll
            for (int oi = 0; oi < WD; ++oi)
                acc[m][oi] += xn * W[(size_t)m * OO + o0 + oi];
    }

    float uval[WD], hval[WD];
    if (!GATE) {
        #pragma unroll
        for (int oi = 0; oi < WD; ++oi) {
            uval[oi] = g[(size_t)((b << 7) + 64 + o0 + oi) * 512 + n];
            hval[oi] = hOld[(size_t)((b << 6) + o0 + oi) * 512 + n];
        }
    }

    __syncthreads();     // phase 1 done everywhere; Wt now dead, tiles writable

    // ---- stage Z2 -> Ta, Z4 -> Tc ----
    if constexpr (WD == 8) {
        *(float4*)&Ta[n * 8 + (n & 1) * 4] =
            make_float4(acc[2][0], acc[2][1], acc[2][2], acc[2][3]);
        *(float4*)&Ta[n * 8 + ((n & 1) ^ 1) * 4] =
            make_float4(acc[2][4], acc[2][5], acc[2][6], acc[2][7]);
        *(float4*)&Tc[n * 8 + (n & 1) * 4] =
            make_float4(acc[4][0], acc[4][1], acc[4][2], acc[4][3]);
        *(float4*)&Tc[n * 8 + ((n & 1) ^ 1) * 4] =
            make_float4(acc[4][4], acc[4][5], acc[4][6], acc[4][7]);
    } else {
        *(float4*)&Ta[n * 4] = make_float4(acc[2][0], acc[2][1], acc[2][2], acc[2][3]);
        *(float4*)&Tc[n * 4] = make_float4(acc[4][0], acc[4][1], acc[4][2], acc[4][3]);
    }

    auto gather = [&](const float* T, int s, float* o) {
        int cnt = s ? cnt1 : cnt0;
        const int2* e0 = ell + s * NN + n;
        float a0[WD];
        #pragma unroll
        for (int i = 0; i < WD; ++i) a0[i] = 0.f;
        #pragma unroll 2
        for (int p = 0; p < cnt; ++p) {
            int2 e = e0[(size_t)p << 10];
            int j = e.x;
            float v = __int_as_float(e.y);
            if constexpr (WD == 8) {
                float4 x0 = *(const float4*)&T[j * 8 + (j & 1) * 4];
                float4 x1 = *(const float4*)&T[j * 8 + ((j & 1) ^ 1) * 4];
                a0[0] += v * x0.x; a0[1] += v * x0.y; a0[2] += v * x0.z; a0[3] += v * x0.w;
                a0[4] += v * x1.x; a0[5] += v * x1.y; a0[6] += v * x1.z; a0[7] += v * x1.w;
            } else {
                float4 x0 = *(const float4*)&T[j * 4];
                a0[0] += v * x0.x; a0[1] += v * x0.y; a0[2] += v * x0.z; a0[3] += v * x0.w;
            }
        }
        #pragma unroll
        for (int i = 0; i < WD; ++i) o[i] = a0[i];
    };
    auto put = [&](float* T, const float* y) {
        if constexpr (WD == 8) {
            *(float4*)&T[n * 8 + (n & 1) * 4]       = make_float4(y[0], y[1], y[2], y[3]);
            *(float4*)&T[n * 8 + ((n & 1) ^ 1) * 4] = make_float4(y[4], y[5], y[6], y[7]);
        } else {
            *(float4*)&T[n * 4] = make_float4(y[0], y[1], y[2], y[3]);
        }
    };

    float g2[WD], g4[WD], t1[WD];

    __syncthreads();                    // bar: Ta/Tc staged

    gather(Ta, 0, t1);                  // S1 Z2
    #pragma unroll
    for (int oi = 0; oi < WD; ++oi) acc[1][oi] += 2.f * t1[oi];   // y1 = Z1+2 S1 Z2
    gather(Tc, 1, t1);                  // S2 Z4
    #pragma unroll
    for (int oi = 0; oi < WD; ++oi) acc[3][oi] += 2.f * t1[oi];   // y2 = Z3+2 S2 Z4

    __syncthreads();                    // hop-1 reads done

    put(Tb, acc[1]);
    put(Tc, acc[3]);

    __syncthreads();                    // y tiles ready

    gather(Tb, 0, g2);                  // S1 y1
    gather(Tc, 1, g4);                  // S2 y2

    #pragma unroll
    for (int oi = 0; oi < WD; ++oi) {
        float accf = acc[0][oi] + g2[oi] + g4[oi] + bias[o0 + oi];
        if (GATE) {
            gout[(size_t)((b << 7) + o0 + oi) * 512 + n] = sigm(accf);
        } else {
            float cv = tanhf(accf);
            hNew[(size_t)((b << 6) + o0 + oi) * 512 + n] =
                uval[oi] * hval[oi] + (1.f - uval[oi]) * cv;
        }
    }
}

// ---------------- projection ----------------------------------------------------
__global__ void proj_kernel(const float* __restrict__ h1, const float* __restrict__ pW,
                            const float* __restrict__ pb, float* __restrict__ outt) {
    int r = blockIdx.x * 256 + threadIdx.x;
    if (r >= RTOT) return;
    int b = r >> 9, n = r & 511;
    float acc = pb[0];
    #pragma unroll 16
    for (int u = 0; u < 64; ++u)
        acc += h1[(size_t)((b << 6) + u) * 512 + n] * pW[u];
    outt[b * NN + n] = acc;
}

// ================================================================================
extern "C" void kernel_launch(void* const* d_in, const int* in_sizes, int n_in,
                              void* d_out, int out_size, void* d_ws, size_t ws_size,
                              hipStream_t stream) {
    const float* inputs   = (const float*)d_in[0];
    const float* supports = (const float*)d_in[1];
    const float* enc0_Wg = (const float*)d_in[2];
    const float* enc0_bg = (const float*)d_in[3];
    const float* enc0_Wc = (const float*)d_in[4];
    const float* enc0_bc = (const float*)d_in[5];
    const float* enc1_Wg = (const float*)d_in[6];
    const float* enc1_bg = (const float*)d_in[7];
    const float* enc1_Wc = (const float*)d_in[8];
    const float* enc1_bc = (const float*)d_in[9];
    const float* dec0_Wg = (const float*)d_in[10];
    const float* dec0_bg = (const float*)d_in[11];
    const float* dec0_Wc = (const float*)d_in[12];
    const float* dec0_bc = (const float*)d_in[13];
    const float* dec1_Wg = (const float*)d_in[14];
    const float* dec1_bg = (const float*)d_in[15];
    const float* dec1_Wc = (const float*)d_in[16];
    const float* dec1_bc = (const float*)d_in[17];
    const float* projW   = (const float*)d_in[18];
    const float* projb   = (const float*)d_in[19];
    float* out = (float*)d_out;

    char* wsb = (char*)d_ws;
    size_t off = 0;
    auto alloc = [&](size_t bytes) -> char* {
        char* p = wsb + off;
        off = (off + bytes + 255) & ~(size_t)255;
        return p;
    };
    int2*  ell   = (int2*)alloc((size_t)CAP * 1024 * 8);
    int*   ecnt  = (int*)alloc((size_t)2 * NN * 4);
    float* h0a   = (float*)alloc((size_t)RTOT * UU * 4);     // [b][u][n]
    float* h1a   = (float*)alloc((size_t)RTOT * UU * 4);
    float* xzero = (float*)alloc((size_t)RTOT * 4);
    float* h0b   = (float*)alloc((size_t)RTOT * UU * 4);
    float* h1b   = (float*)alloc((size_t)RTOT * UU * 4);
    float* g     = (float*)alloc((size_t)RTOT * 128 * 4);    // [b][go][n]
    float* m_e0g = (float*)alloc((size_t)65 * 5 * 128 * 4);
    float* m_e0c = (float*)alloc((size_t)65 * 5 * 64 * 4);
    float* m_e1g = (float*)alloc((size_t)128 * 5 * 128 * 4);
    float* m_e1c = (float*)alloc((size_t)128 * 5 * 64 * 4);
    float* m_d0g = (float*)alloc((size_t)65 * 5 * 128 * 4);
    float* m_d0c = (float*)alloc((size_t)65 * 5 * 64 * 4);
    float* m_d1g = (float*)alloc((size_t)128 * 5 * 128 * 4);
    float* m_d1c = (float*)alloc((size_t)128 * 5 * 64 * 4);
    if (off > ws_size) return;

    build_ell<<<256, 256, 0, stream>>>(supports, ell, ecnt);
    {
        int nz = RTOT * UU * 2 + RTOT;  // h0a, h1a, xzero contiguous
        zero_kernel<<<(nz + 255) / 256, 256, 0, stream>>>(h0a, nz);
    }
    wsub<<<(65 * 128 + 255) / 256, 256, 0, stream>>>(enc0_Wg, m_e0g, 65, 128);
    wsub<<<(65 * 64 + 255) / 256, 256, 0, stream>>>(enc0_Wc, m_e0c, 65, 64);
    wsub<<<(128 * 128 + 255) / 256, 256, 0, stream>>>(enc1_Wg, m_e1g, 128, 128);
    wsub<<<(128 * 64 + 255) / 256, 256, 0, stream>>>(enc1_Wc, m_e1c, 128, 64);
    wsub<<<(65 * 128 + 255) / 256, 256, 0, stream>>>(dec0_Wg, m_d0g, 65, 128);
    wsub<<<(65 * 64 + 255) / 256, 256, 0, stream>>>(dec0_Wc, m_d0c, 65, 64);
    wsub<<<(128 * 128 + 255) / 256, 256, 0, stream>>>(dec1_Wg, m_d1g, 128, 128);
    wsub<<<(128 * 64 + 255) / 256, 256, 0, stream>>>(dec1_Wc, m_d1c, 128, 64);

    float *h0c = h0a, *h0n = h0b, *h1c = h1a, *h1n = h1b;

    auto cell_l0 = [&](const float* x_bn, const float* Wg_, const float* bg_,
                       const float* Wc_, const float* bc_) {
        fused<true, true><<<512, 512, 0, stream>>>(h0c, nullptr, nullptr, Wg_, x_bn,
                                                   bg_, ell, ecnt, g, nullptr, nullptr);
        fused<true, false><<<512, 512, 0, stream>>>(h0c, nullptr, g, Wc_, x_bn,
                                                    bc_, ell, ecnt, nullptr, h0c, h0n);
        float* t = h0c; h0c = h0n; h0n = t;
    };
    auto cell_l1 = [&](const float* Wg_, const float* bg_,
                       const float* Wc_, const float* bc_) {
        fused<false, true><<<512, 512, 0, stream>>>(h0c, h1c, nullptr, Wg_, nullptr,
                                                    bg_, ell, ecnt, g, nullptr, nullptr);
        fused<false, false><<<512, 512, 0, stream>>>(h0c, h1c, g, Wc_, nullptr,
                                                     bc_, ell, ecnt, nullptr, h1c, h1n);
        float* t = h1c; h1c = h1n; h1n = t;
    };

    for (int t = 0; t < TT; ++t) {
        cell_l0(inputs + (size_t)t * BB * NN, m_e0g, enc0_bg, m_e0c, enc0_bc);
        cell_l1(m_e1g, enc1_bg, m_e1c, enc1_bc);
    }
    for (int t = 0; t < HH; ++t) {
        const float* xin = (t == 0) ? xzero : (out + (size_t)(t - 1) * BB * NN);
        cell_l0(xin, m_d0g, dec0_bg, m_d0c, dec0_bc);
        cell_l1(m_d1g, dec1_bg, m_d1c, dec1_bc);
        proj_kernel<<<(RTOT + 255) / 256, 256, 0, stream>>>(h1c, projW, projb,
                                                            out + (size_t)t * BB * NN);
    }
}

// Round 12
// 4882.663 us; speedup vs baseline: 1.4010x; 1.1501x over previous
//
#include <hip/hip_runtime.h>
#include <math.h>

#define NN 512
#define BB 32
#define TT 12
#define HH 12
#define UU 64
#define CAP 128
#define RTOT (NN * BB)          // 16384 rows

__device__ __forceinline__ float sigm(float x) { return 1.f / (1.f + expf(-x)); }

// ---------------- ELL build: int2 {idx, val_bits} at [p*1024 + s*512 + row] -----
__global__ __launch_bounds__(256) void build_ell(const float* __restrict__ sup,
                                                 int2* __restrict__ ell,
                                                 int* __restrict__ ecnt) {
    int wave = (blockIdx.x * blockDim.x + threadIdx.x) >> 6;
    int lane = threadIdx.x & 63;
    if (wave >= 2 * NN) return;
    const float* row = sup + (size_t)wave * NN;
    int base = 0;
    for (int k = 0; k < NN / 64; ++k) {
        float v = row[k * 64 + lane];
        unsigned long long m = __ballot(v != 0.0f);
        int pre = __popcll(m & ((1ull << lane) - 1ull));
        if (v != 0.0f) {
            int pos = base + pre;
            if (pos < CAP)
                ell[(size_t)pos * 1024 + wave] = make_int2(k * 64 + lane, __float_as_int(v));
        }
        base += __popcll(m);
    }
    if (lane == 0) ecnt[wave] = base < CAP ? base : CAP;
}

__global__ void zero_kernel(float* __restrict__ p, int n) {
    int i = blockIdx.x * 256 + threadIdx.x;
    if (i < n) p[i] = 0.0f;
}

// ---------------- weight prep: permute to [oq][m][c][WD] + x-row table ----------
// Wmod semantics: m=0 slot holds W0-W2-W4 (Chebyshev pre-subtraction).
// For L0, h-rows are src rows 1..C; x-row (src row 0) goes to dstX[oq][m][oi].
__global__ void wprep(const float* __restrict__ src, float* __restrict__ dstP,
                      float* __restrict__ dstX, int C, int OO, int WD, int L0) {
    int idx = blockIdx.x * 256 + threadIdx.x;
    int total = 5 * C * OO;
    if (idx >= total) return;
    int oi = idx % WD;
    int rem = idx / WD;
    int c = rem % C;
    int rem2 = rem / C;
    int m = rem2 % 5;
    int oq = rem2 / 5;
    int o = oq * WD + oi;
    int crow = L0 ? (c + 1) : c;
    size_t base = (size_t)crow * 5 * OO + o;
    float v;
    if (m == 0) v = src[base] - src[base + 2 * OO] - src[base + 4 * OO];
    else        v = src[base + (size_t)m * OO];
    dstP[idx] = v;
    if (L0 && c == 0) {
        size_t b0 = (size_t)o;       // crow = 0
        float xvv;
        if (m == 0) xvv = src[b0] - src[b0 + 2 * OO] - src[b0 + 4 * OO];
        else        xvv = src[b0 + (size_t)m * OO];
        dstX[(oq * 5 + m) * WD + oi] = xvv;
    }
}

// ---------------- fused gconv: GEMM-in-registers + Chebyshev combine ------------
// Phase 1: acc[m][oi] = sum_c A[c][n] * Wp[oq][m][c][oi]; W read wave-uniform
// from GLOBAL (scalar-cache path) — no LDS in phase 1. Phase 2: LDS tiles for
// the 4 sparse gathers; out = Z024 + S1(Z1+2S1Z2) + S2(Z3+2S2Z4) + bias.
// GATE: g = sigmoid(.) (WD=8). else: h_new = u*h_old + (1-u)*tanh(.) (WD=4).
template<bool L0, bool GATE>
__global__ __launch_bounds__(512) void fused(const float* __restrict__ hA,
                                             const float* __restrict__ hB,
                                             const float* __restrict__ g,
                                             const float* __restrict__ Wp,
                                             const float* __restrict__ Xr,
                                             const float* __restrict__ xv,
                                             const float* __restrict__ bias,
                                             const int2* __restrict__ ell,
                                             const int* __restrict__ ecnt,
                                             float* __restrict__ gout,
                                             const float* __restrict__ hOld,
                                             float* __restrict__ hNew) {
    constexpr int C  = L0 ? 64 : 128;
    constexpr int WD = GATE ? 8 : 4;

    __shared__ float Ta[512 * WD];
    __shared__ float Tb[512 * WD];
    __shared__ float Tc[512 * WD];

    int bid = blockIdx.x;
    int swz = (bid & 7) * 64 + (bid >> 3);  // XCD-contiguous (512 blocks, %8==0)
    int b = swz >> 4, oq = swz & 15;
    int o0 = oq * WD;
    int n = threadIdx.x;
    int cnt0 = ecnt[n], cnt1 = ecnt[NN + n];
    float xn = L0 ? xv[b * 512 + n] : 0.f;

    // ---- phase 1: GEMM in registers; W via uniform global reads ----
    const float* Wb = Wp + (size_t)oq * 5 * C * WD;
    float acc[5][WD];
    #pragma unroll
    for (int m = 0; m < 5; ++m)
        #pragma unroll
        for (int oi = 0; oi < WD; ++oi) acc[m][oi] = 0.f;

    #pragma unroll 2
    for (int c = 0; c < C; ++c) {
        float a;
        if (L0) {
            a = hA[(size_t)((b << 6) + c) * 512 + n];
            if (!GATE) a *= g[(size_t)((b << 7) + c) * 512 + n];
        } else {
            if (c < 64) {
                a = hA[(size_t)((b << 6) + c) * 512 + n];
            } else {
                int u = c - 64;
                a = hB[(size_t)((b << 6) + u) * 512 + n];
                if (!GATE) a *= g[(size_t)((b << 7) + u) * 512 + n];
            }
        }
        #pragma unroll
        for (int m = 0; m < 5; ++m) {
            const float* wrow = Wb + ((size_t)m * C + c) * WD;
            #pragma unroll
            for (int oi = 0; oi < WD; ++oi)
                acc[m][oi] += a * wrow[oi];
        }
    }

    // rank-1 x-term (L0) from x-row table
    if (L0) {
        const float* xr = Xr + (size_t)oq * 5 * WD;
        #pragma unroll
        for (int m = 0; m < 5; ++m)
            #pragma unroll
            for (int oi = 0; oi < WD; ++oi)
                acc[m][oi] += xn * xr[m * WD + oi];
    }

    float uval[WD], hval[WD];
    if (!GATE) {
        #pragma unroll
        for (int oi = 0; oi < WD; ++oi) {
            uval[oi] = g[(size_t)((b << 7) + 64 + o0 + oi) * 512 + n];
            hval[oi] = hOld[(size_t)((b << 6) + o0 + oi) * 512 + n];
        }
    }

    // ---- stage Z2 -> Ta, Z4 -> Tc ----
    if constexpr (WD == 8) {
        *(float4*)&Ta[n * 8 + (n & 1) * 4] =
            make_float4(acc[2][0], acc[2][1], acc[2][2], acc[2][3]);
        *(float4*)&Ta[n * 8 + ((n & 1) ^ 1) * 4] =
            make_float4(acc[2][4], acc[2][5], acc[2][6], acc[2][7]);
        *(float4*)&Tc[n * 8 + (n & 1) * 4] =
            make_float4(acc[4][0], acc[4][1], acc[4][2], acc[4][3]);
        *(float4*)&Tc[n * 8 + ((n & 1) ^ 1) * 4] =
            make_float4(acc[4][4], acc[4][5], acc[4][6], acc[4][7]);
    } else {
        *(float4*)&Ta[n * 4] = make_float4(acc[2][0], acc[2][1], acc[2][2], acc[2][3]);
        *(float4*)&Tc[n * 4] = make_float4(acc[4][0], acc[4][1], acc[4][2], acc[4][3]);
    }

    auto gather = [&](const float* T, int s, float* o) {
        int cnt = s ? cnt1 : cnt0;
        const int2* e0 = ell + s * NN + n;
        float a0[WD];
        #pragma unroll
        for (int i = 0; i < WD; ++i) a0[i] = 0.f;
        #pragma unroll 2
        for (int p = 0; p < cnt; ++p) {
            int2 e = e0[(size_t)p << 10];
            int j = e.x;
            float v = __int_as_float(e.y);
            if constexpr (WD == 8) {
                float4 x0 = *(const float4*)&T[j * 8 + (j & 1) * 4];
                float4 x1 = *(const float4*)&T[j * 8 + ((j & 1) ^ 1) * 4];
                a0[0] += v * x0.x; a0[1] += v * x0.y; a0[2] += v * x0.z; a0[3] += v * x0.w;
                a0[4] += v * x1.x; a0[5] += v * x1.y; a0[6] += v * x1.z; a0[7] += v * x1.w;
            } else {
                float4 x0 = *(const float4*)&T[j * 4];
                a0[0] += v * x0.x; a0[1] += v * x0.y; a0[2] += v * x0.z; a0[3] += v * x0.w;
            }
        }
        #pragma unroll
        for (int i = 0; i < WD; ++i) o[i] = a0[i];
    };
    auto put = [&](float* T, const float* y) {
        if constexpr (WD == 8) {
            *(float4*)&T[n * 8 + (n & 1) * 4]       = make_float4(y[0], y[1], y[2], y[3]);
            *(float4*)&T[n * 8 + ((n & 1) ^ 1) * 4] = make_float4(y[4], y[5], y[6], y[7]);
        } else {
            *(float4*)&T[n * 4] = make_float4(y[0], y[1], y[2], y[3]);
        }
    };

    float g2[WD], g4[WD], t1[WD];

    __syncthreads();                    // bar 1: Ta/Tc staged

    gather(Ta, 0, t1);                  // S1 Z2
    #pragma unroll
    for (int oi = 0; oi < WD; ++oi) acc[1][oi] += 2.f * t1[oi];   // y1 = Z1+2 S1 Z2
    gather(Tc, 1, t1);                  // S2 Z4
    #pragma unroll
    for (int oi = 0; oi < WD; ++oi) acc[3][oi] += 2.f * t1[oi];   // y2 = Z3+2 S2 Z4

    __syncthreads();                    // bar 2: hop-1 reads done

    put(Tb, acc[1]);
    put(Tc, acc[3]);

    __syncthreads();                    // bar 3: y tiles ready

    gather(Tb, 0, g2);                  // S1 y1
    gather(Tc, 1, g4);                  // S2 y2

    #pragma unroll
    for (int oi = 0; oi < WD; ++oi) {
        float accf = acc[0][oi] + g2[oi] + g4[oi] + bias[o0 + oi];
        if (GATE) {
            gout[(size_t)((b << 7) + o0 + oi) * 512 + n] = sigm(accf);
        } else {
            float cv = tanhf(accf);
            hNew[(size_t)((b << 6) + o0 + oi) * 512 + n] =
                uval[oi] * hval[oi] + (1.f - uval[oi]) * cv;
        }
    }
}

// ---------------- projection ----------------------------------------------------
__global__ void proj_kernel(const float* __restrict__ h1, const float* __restrict__ pW,
                            const float* __restrict__ pb, float* __restrict__ outt) {
    int r = blockIdx.x * 256 + threadIdx.x;
    if (r >= RTOT) return;
    int b = r >> 9, n = r & 511;
    float acc = pb[0];
    #pragma unroll 16
    for (int u = 0; u < 64; ++u)
        acc += h1[(size_t)((b << 6) + u) * 512 + n] * pW[u];
    outt[b * NN + n] = acc;
}

// ================================================================================
extern "C" void kernel_launch(void* const* d_in, const int* in_sizes, int n_in,
                              void* d_out, int out_size, void* d_ws, size_t ws_size,
                              hipStream_t stream) {
    const float* inputs   = (const float*)d_in[0];
    const float* supports = (const float*)d_in[1];
    const float* enc0_Wg = (const float*)d_in[2];
    const float* enc0_bg = (const float*)d_in[3];
    const float* enc0_Wc = (const float*)d_in[4];
    const float* enc0_bc = (const float*)d_in[5];
    const float* enc1_Wg = (const float*)d_in[6];
    const float* enc1_bg = (const float*)d_in[7];
    const float* enc1_Wc = (const float*)d_in[8];
    const float* enc1_bc = (const float*)d_in[9];
    const float* dec0_Wg = (const float*)d_in[10];
    const float* dec0_bg = (const float*)d_in[11];
    const float* dec0_Wc = (const float*)d_in[12];
    const float* dec0_bc = (const float*)d_in[13];
    const float* dec1_Wg = (const float*)d_in[14];
    const float* dec1_bg = (const float*)d_in[15];
    const float* dec1_Wc = (const float*)d_in[16];
    const float* dec1_bc = (const float*)d_in[17];
    const float* projW   = (const float*)d_in[18];
    const float* projb   = (const float*)d_in[19];
    float* out = (float*)d_out;

    char* wsb = (char*)d_ws;
    size_t off = 0;
    auto alloc = [&](size_t bytes) -> char* {
        char* p = wsb + off;
        off = (off + bytes + 255) & ~(size_t)255;
        return p;
    };
    int2*  ell   = (int2*)alloc((size_t)CAP * 1024 * 8);
    int*   ecnt  = (int*)alloc((size_t)2 * NN * 4);
    float* h0a   = (float*)alloc((size_t)RTOT * UU * 4);     // [b][u][n]
    float* h1a   = (float*)alloc((size_t)RTOT * UU * 4);
    float* xzero = (float*)alloc((size_t)RTOT * 4);
    float* h0b   = (float*)alloc((size_t)RTOT * UU * 4);
    float* h1b   = (float*)alloc((size_t)RTOT * UU * 4);
    float* g     = (float*)alloc((size_t)RTOT * 128 * 4);    // [b][go][n]
    float* p_e0g = (float*)alloc((size_t)5 * 64 * 128 * 4);
    float* x_e0g = (float*)alloc((size_t)16 * 5 * 8 * 4);
    float* p_e0c = (float*)alloc((size_t)5 * 64 * 64 * 4);
    float* x_e0c = (float*)alloc((size_t)16 * 5 * 4 * 4);
    float* p_e1g = (float*)alloc((size_t)5 * 128 * 128 * 4);
    float* p_e1c = (float*)alloc((size_t)5 * 128 * 64 * 4);
    float* p_d0g = (float*)alloc((size_t)5 * 64 * 128 * 4);
    float* x_d0g = (float*)alloc((size_t)16 * 5 * 8 * 4);
    float* p_d0c = (float*)alloc((size_t)5 * 64 * 64 * 4);
    float* x_d0c = (float*)alloc((size_t)16 * 5 * 4 * 4);
    float* p_d1g = (float*)alloc((size_t)5 * 128 * 128 * 4);
    float* p_d1c = (float*)alloc((size_t)5 * 128 * 64 * 4);
    float* xdum  = (float*)alloc((size_t)16 * 5 * 8 * 4);
    if (off > ws_size) return;

    build_ell<<<256, 256, 0, stream>>>(supports, ell, ecnt);
    {
        int nz = RTOT * UU * 2 + RTOT;  // h0a, h1a, xzero contiguous
        zero_kernel<<<(nz + 255) / 256, 256, 0, stream>>>(h0a, nz);
    }
    // weight prep (permuted layout + x-row tables)
    wprep<<<(5 * 64 * 128 + 255) / 256, 256, 0, stream>>>(enc0_Wg, p_e0g, x_e0g, 64, 128, 8, 1);
    wprep<<<(5 * 64 * 64 + 255) / 256, 256, 0, stream>>>(enc0_Wc, p_e0c, x_e0c, 64, 64, 4, 1);
    wprep<<<(5 * 128 * 128 + 255) / 256, 256, 0, stream>>>(enc1_Wg, p_e1g, xdum, 128, 128, 8, 0);
    wprep<<<(5 * 128 * 64 + 255) / 256, 256, 0, stream>>>(enc1_Wc, p_e1c, xdum, 128, 64, 4, 0);
    wprep<<<(5 * 64 * 128 + 255) / 256, 256, 0, stream>>>(dec0_Wg, p_d0g, x_d0g, 64, 128, 8, 1);
    wprep<<<(5 * 64 * 64 + 255) / 256, 256, 0, stream>>>(dec0_Wc, p_d0c, x_d0c, 64, 64, 4, 1);
    wprep<<<(5 * 128 * 128 + 255) / 256, 256, 0, stream>>>(dec1_Wg, p_d1g, xdum, 128, 128, 8, 0);
    wprep<<<(5 * 128 * 64 + 255) / 256, 256, 0, stream>>>(dec1_Wc, p_d1c, xdum, 128, 64, 4, 0);

    float *h0c = h0a, *h0n = h0b, *h1c = h1a, *h1n = h1b;

    auto cell_l0 = [&](const float* x_bn, const float* Wg_, const float* Xg_,
                       const float* bg_, const float* Wc_, const float* Xc_,
                       const float* bc_) {
        fused<true, true><<<512, 512, 0, stream>>>(h0c, nullptr, nullptr, Wg_, Xg_, x_bn,
                                                   bg_, ell, ecnt, g, nullptr, nullptr);
        fused<true, false><<<512, 512, 0, stream>>>(h0c, nullptr, g, Wc_, Xc_, x_bn,
                                                    bc_, ell, ecnt, nullptr, h0c, h0n);
        float* t = h0c; h0c = h0n; h0n = t;
    };
    auto cell_l1 = [&](const float* Wg_, const float* bg_,
                       const float* Wc_, const float* bc_) {
        fused<false, true><<<512, 512, 0, stream>>>(h0c, h1c, nullptr, Wg_, nullptr, nullptr,
                                                    bg_, ell, ecnt, g, nullptr, nullptr);
        fused<false, false><<<512, 512, 0, stream>>>(h0c, h1c, g, Wc_, nullptr, nullptr,
                                                     bc_, ell, ecnt, nullptr, h1c, h1n);
        float* t = h1c; h1c = h1n; h1n = t;
    };

    for (int t = 0; t < TT; ++t) {
        cell_l0(inputs + (size_t)t * BB * NN, p_e0g, x_e0g, enc0_bg, p_e0c, x_e0c, enc0_bc);
        cell_l1(p_e1g, enc1_bg, p_e1c, enc1_bc);
    }
    for (int t = 0; t < HH; ++t) {
        const float* xin = (t == 0) ? xzero : (out + (size_t)(t - 1) * BB * NN);
        cell_l0(xin, p_d0g, x_d0g, dec0_bg, p_d0c, x_d0c, dec0_bc);
        cell_l1(p_d1g, dec1_bg, p_d1c, dec1_bc);
        proj_kernel<<<(RTOT + 255) / 256, 256, 0, stream>>>(h1c, projW, projb,
                                                            out + (size_t)t * BB * NN);
    }
}

// Round 13
// 4793.678 us; speedup vs baseline: 1.4270x; 1.0186x over previous
//
#include <hip/hip_runtime.h>
#include <math.h>

#define NN 512
#define BB 32
#define TT 12
#define HH 12
#define UU 64
#define CAP 128
#define RTOT (NN * BB)          // 16384 rows

__device__ __forceinline__ float sigm(float x) { return 1.f / (1.f + expf(-x)); }

// ---------------- ELL build with pre-baked LDS byte offsets ---------------------
// ell8: {j*32 + (j&1)*16, val}  (WD=8 tiles; other half = off ^ 16)
// ell4: {j*16, val}             (WD=4 tiles)
__global__ __launch_bounds__(256) void build_ell(const float* __restrict__ sup,
                                                 int2* __restrict__ ell8,
                                                 int2* __restrict__ ell4,
                                                 int* __restrict__ ecnt) {
    int wave = (blockIdx.x * blockDim.x + threadIdx.x) >> 6;
    int lane = threadIdx.x & 63;
    if (wave >= 2 * NN) return;
    const float* row = sup + (size_t)wave * NN;
    int base = 0;
    for (int k = 0; k < NN / 64; ++k) {
        float v = row[k * 64 + lane];
        unsigned long long m = __ballot(v != 0.0f);
        int pre = __popcll(m & ((1ull << lane) - 1ull));
        if (v != 0.0f) {
            int pos = base + pre;
            if (pos < CAP) {
                int j = k * 64 + lane;
                int vb = __float_as_int(v);
                ell8[(size_t)pos * 1024 + wave] = make_int2(j * 32 + (j & 1) * 16, vb);
                ell4[(size_t)pos * 1024 + wave] = make_int2(j * 16, vb);
            }
        }
        base += __popcll(m);
    }
    if (lane == 0) ecnt[wave] = base < CAP ? base : CAP;
}

__global__ void zero_kernel(float* __restrict__ p, int n) {
    int i = blockIdx.x * 256 + threadIdx.x;
    if (i < n) p[i] = 0.0f;
}

// ---------------- weight prep: permute to [oq][m][c][WD] + x-row table ----------
// Wmod semantics: m=0 slot holds W0-W2-W4 (Chebyshev pre-subtraction).
__global__ void wprep(const float* __restrict__ src, float* __restrict__ dstP,
                      float* __restrict__ dstX, int C, int OO, int WD, int L0) {
    int idx = blockIdx.x * 256 + threadIdx.x;
    int total = 5 * C * OO;
    if (idx >= total) return;
    int oi = idx % WD;
    int rem = idx / WD;
    int c = rem % C;
    int rem2 = rem / C;
    int m = rem2 % 5;
    int oq = rem2 / 5;
    int o = oq * WD + oi;
    int crow = L0 ? (c + 1) : c;
    size_t base = (size_t)crow * 5 * OO + o;
    float v;
    if (m == 0) v = src[base] - src[base + 2 * OO] - src[base + 4 * OO];
    else        v = src[base + (size_t)m * OO];
    dstP[idx] = v;
    if (L0 && c == 0) {
        size_t b0 = (size_t)o;       // crow = 0
        float xvv;
        if (m == 0) xvv = src[b0] - src[b0 + 2 * OO] - src[b0 + 4 * OO];
        else        xvv = src[b0 + (size_t)m * OO];
        dstX[(oq * 5 + m) * WD + oi] = xvv;
    }
}

// ---------------- fused gconv: GEMM-in-registers + Chebyshev combine ------------
// Phase 1: acc[m][oi] = bias-init + sum_c A[c][n]*Wp[oq][m][c][oi]; W wave-uniform
// global (scalar cache). Phase 2: 2 LDS tiles, 4 gathers (pre-baked offsets);
// out = Z024 + S1(Z1+2S1Z2) + S2(Z3+2S2Z4).
// GATE (WD=8): r-half -> g[u<64] = sigm(.)*h (rh-fusion); u-half -> g[u>=64]=sigm(.)
// CAND (WD=4): h_new = u*h_old + (1-u)*tanh(.); A loads rh directly from g.
template<bool L0, bool GATE>
__global__ __launch_bounds__(512) void fused(const float* __restrict__ hA,
                                             const float* __restrict__ hB,
                                             const float* __restrict__ g,
                                             const float* __restrict__ Wp,
                                             const float* __restrict__ Xr,
                                             const float* __restrict__ xv,
                                             const float* __restrict__ bias,
                                             const int2* __restrict__ ell,
                                             const int* __restrict__ ecnt,
                                             float* __restrict__ gout,
                                             const float* __restrict__ hOld,
                                             float* __restrict__ hNew) {
    constexpr int C  = L0 ? 64 : 128;
    constexpr int WD = GATE ? 8 : 4;

    __shared__ float S[512 * WD * 2];
    float* T0 = S;
    float* T1 = S + 512 * WD;

    int bid = blockIdx.x;
    int swz = (bid & 7) * 64 + (bid >> 3);  // XCD-contiguous (512 blocks, %8==0)
    int b = swz >> 4, oq = swz & 15;
    int o0 = oq * WD;
    int n = threadIdx.x;
    int cnt0 = ecnt[n], cnt1 = ecnt[NN + n];
    float xn = L0 ? xv[b * 512 + n] : 0.f;

    // ---- phase 1: GEMM in registers; W via uniform global reads ----
    const float* Wb = Wp + (size_t)oq * 5 * C * WD;
    float acc[5][WD];
    #pragma unroll
    for (int oi = 0; oi < WD; ++oi) acc[0][oi] = bias[o0 + oi];   // bias-init
    #pragma unroll
    for (int m = 1; m < 5; ++m)
        #pragma unroll
        for (int oi = 0; oi < WD; ++oi) acc[m][oi] = 0.f;

    #pragma unroll 2
    for (int c = 0; c < C; ++c) {
        float a;
        if (L0) {
            if (GATE) a = hA[(size_t)((b << 6) + c) * 512 + n];
            else      a = g[(size_t)((b << 7) + c) * 512 + n];          // rh
        } else {
            if (c < 64) {
                a = hA[(size_t)((b << 6) + c) * 512 + n];
            } else {
                int u = c - 64;
                if (GATE) a = hB[(size_t)((b << 6) + u) * 512 + n];
                else      a = g[(size_t)((b << 7) + u) * 512 + n];      // rh
            }
        }
        #pragma unroll
        for (int m = 0; m < 5; ++m) {
            const float* wrow = Wb + ((size_t)m * C + c) * WD;
            #pragma unroll
            for (int oi = 0; oi < WD; ++oi)
                acc[m][oi] += a * wrow[oi];
        }
    }

    // rank-1 x-term (L0) from x-row table
    if (L0) {
        const float* xr = Xr + (size_t)oq * 5 * WD;
        #pragma unroll
        for (int m = 0; m < 5; ++m)
            #pragma unroll
            for (int oi = 0; oi < WD; ++oi)
                acc[m][oi] += xn * xr[m * WD + oi];
    }

    float uval[WD], hval[WD];
    if (!GATE) {
        #pragma unroll
        for (int oi = 0; oi < WD; ++oi) {
            uval[oi] = g[(size_t)((b << 7) + 64 + o0 + oi) * 512 + n];
            hval[oi] = hOld[(size_t)((b << 6) + o0 + oi) * 512 + n];
        }
    }

    // ---- stage Z2 -> T0, Z4 -> T1 ----
    if constexpr (WD == 8) {
        *(float4*)&T0[n * 8 + (n & 1) * 4] =
            make_float4(acc[2][0], acc[2][1], acc[2][2], acc[2][3]);
        *(float4*)&T0[n * 8 + ((n & 1) ^ 1) * 4] =
            make_float4(acc[2][4], acc[2][5], acc[2][6], acc[2][7]);
        *(float4*)&T1[n * 8 + (n & 1) * 4] =
            make_float4(acc[4][0], acc[4][1], acc[4][2], acc[4][3]);
        *(float4*)&T1[n * 8 + ((n & 1) ^ 1) * 4] =
            make_float4(acc[4][4], acc[4][5], acc[4][6], acc[4][7]);
    } else {
        *(float4*)&T0[n * 4] = make_float4(acc[2][0], acc[2][1], acc[2][2], acc[2][3]);
        *(float4*)&T1[n * 4] = make_float4(acc[4][0], acc[4][1], acc[4][2], acc[4][3]);
    }

    auto gather = [&](const float* T, int s, float* o) {
        int cnt = s ? cnt1 : cnt0;
        const int2* e0 = ell + s * NN + n;
        const char* Tbyte = (const char*)T;
        float a0[WD];
        #pragma unroll
        for (int i = 0; i < WD; ++i) a0[i] = 0.f;
        #pragma unroll 2
        for (int p = 0; p < cnt; ++p) {
            int2 e = e0[(size_t)p << 10];
            float v = __int_as_float(e.y);
            if constexpr (WD == 8) {
                float4 x0 = *(const float4*)(Tbyte + e.x);
                float4 x1 = *(const float4*)(Tbyte + (e.x ^ 16));
                a0[0] += v * x0.x; a0[1] += v * x0.y; a0[2] += v * x0.z; a0[3] += v * x0.w;
                a0[4] += v * x1.x; a0[5] += v * x1.y; a0[6] += v * x1.z; a0[7] += v * x1.w;
            } else {
                float4 x0 = *(const float4*)(Tbyte + e.x);
                a0[0] += v * x0.x; a0[1] += v * x0.y; a0[2] += v * x0.z; a0[3] += v * x0.w;
            }
        }
        #pragma unroll
        for (int i = 0; i < WD; ++i) o[i] = a0[i];
    };
    auto put = [&](float* T, const float* y) {
        if constexpr (WD == 8) {
            *(float4*)&T[n * 8 + (n & 1) * 4]       = make_float4(y[0], y[1], y[2], y[3]);
            *(float4*)&T[n * 8 + ((n & 1) ^ 1) * 4] = make_float4(y[4], y[5], y[6], y[7]);
        } else {
            *(float4*)&T[n * 4] = make_float4(y[0], y[1], y[2], y[3]);
        }
    };

    float g2[WD], g4[WD], t1[WD];

    __syncthreads();                    // bar 1: T0/T1 staged

    gather(T0, 0, t1);                  // S1 Z2
    #pragma unroll
    for (int oi = 0; oi < WD; ++oi) acc[1][oi] += 2.f * t1[oi];   // y1 = Z1+2 S1 Z2
    gather(T1, 1, t1);                  // S2 Z4
    #pragma unroll
    for (int oi = 0; oi < WD; ++oi) acc[3][oi] += 2.f * t1[oi];   // y2 = Z3+2 S2 Z4

    __syncthreads();                    // bar 2: hop-1 reads done

    put(T0, acc[1]);
    put(T1, acc[3]);

    __syncthreads();                    // bar 3: y tiles ready

    gather(T0, 0, g2);                  // S1 y1
    gather(T1, 1, g4);                  // S2 y2

    #pragma unroll
    for (int oi = 0; oi < WD; ++oi) {
        float accf = acc[0][oi] + g2[oi] + g4[oi];
        if (GATE) {
            float s = sigm(accf);
            if (oq < 8) {               // r-half: write rh = r * h (rh-fusion)
                const float* hG = L0 ? hA : hB;
                float hv = hG[(size_t)((b << 6) + o0 + oi) * 512 + n];
                gout[(size_t)((b << 7) + o0 + oi) * 512 + n] = s * hv;
            } else {
                gout[(size_t)((b << 7) + o0 + oi) * 512 + n] = s;
            }
        } else {
            float cv = tanhf(accf);
            hNew[(size_t)((b << 6) + o0 + oi) * 512 + n] =
                uval[oi] * hval[oi] + (1.f - uval[oi]) * cv;
        }
    }
}

// ---------------- projection ----------------------------------------------------
__global__ void proj_kernel(const float* __restrict__ h1, const float* __restrict__ pW,
                            const float* __restrict__ pb, float* __restrict__ outt) {
    int r = blockIdx.x * 256 + threadIdx.x;
    if (r >= RTOT) return;
    int b = r >> 9, n = r & 511;
    float acc = pb[0];
    #pragma unroll 16
    for (int u = 0; u < 64; ++u)
        acc += h1[(size_t)((b << 6) + u) * 512 + n] * pW[u];
    outt[b * NN + n] = acc;
}

// ================================================================================
extern "C" void kernel_launch(void* const* d_in, const int* in_sizes, int n_in,
                              void* d_out, int out_size, void* d_ws, size_t ws_size,
                              hipStream_t stream) {
    const float* inputs   = (const float*)d_in[0];
    const float* supports = (const float*)d_in[1];
    const float* enc0_Wg = (const float*)d_in[2];
    const float* enc0_bg = (const float*)d_in[3];
    const float* enc0_Wc = (const float*)d_in[4];
    const float* enc0_bc = (const float*)d_in[5];
    const float* enc1_Wg = (const float*)d_in[6];
    const float* enc1_bg = (const float*)d_in[7];
    const float* enc1_Wc = (const float*)d_in[8];
    const float* enc1_bc = (const float*)d_in[9];
    const float* dec0_Wg = (const float*)d_in[10];
    const float* dec0_bg = (const float*)d_in[11];
    const float* dec0_Wc = (const float*)d_in[12];
    const float* dec0_bc = (const float*)d_in[13];
    const float* dec1_Wg = (const float*)d_in[14];
    const float* dec1_bg = (const float*)d_in[15];
    const float* dec1_Wc = (const float*)d_in[16];
    const float* dec1_bc = (const float*)d_in[17];
    const float* projW   = (const float*)d_in[18];
    const float* projb   = (const float*)d_in[19];
    float* out = (float*)d_out;

    char* wsb = (char*)d_ws;
    size_t off = 0;
    auto alloc = [&](size_t bytes) -> char* {
        char* p = wsb + off;
        off = (off + bytes + 255) & ~(size_t)255;
        return p;
    };
    int2*  ell8  = (int2*)alloc((size_t)CAP * 1024 * 8);
    int2*  ell4  = (int2*)alloc((size_t)CAP * 1024 * 8);
    int*   ecnt  = (int*)alloc((size_t)2 * NN * 4);
    float* h0a   = (float*)alloc((size_t)RTOT * UU * 4);     // [b][u][n]
    float* h1a   = (float*)alloc((size_t)RTOT * UU * 4);
    float* xzero = (float*)alloc((size_t)RTOT * 4);
    float* h0b   = (float*)alloc((size_t)RTOT * UU * 4);
    float* h1b   = (float*)alloc((size_t)RTOT * UU * 4);
    float* g     = (float*)alloc((size_t)RTOT * 128 * 4);    // [b][u][n]: u<64 rh, u>=64 ugate
    float* p_e0g = (float*)alloc((size_t)5 * 64 * 128 * 4);
    float* x_e0g = (float*)alloc((size_t)16 * 5 * 8 * 4);
    float* p_e0c = (float*)alloc((size_t)5 * 64 * 64 * 4);
    float* x_e0c = (float*)alloc((size_t)16 * 5 * 4 * 4);
    float* p_e1g = (float*)alloc((size_t)5 * 128 * 128 * 4);
    float* p_e1c = (float*)alloc((size_t)5 * 128 * 64 * 4);
    float* p_d0g = (float*)alloc((size_t)5 * 64 * 128 * 4);
    float* x_d0g = (float*)alloc((size_t)16 * 5 * 8 * 4);
    float* p_d0c = (float*)alloc((size_t)5 * 64 * 64 * 4);
    float* x_d0c = (float*)alloc((size_t)16 * 5 * 4 * 4);
    float* p_d1g = (float*)alloc((size_t)5 * 128 * 128 * 4);
    float* p_d1c = (float*)alloc((size_t)5 * 128 * 64 * 4);
    float* xdum  = (float*)alloc((size_t)16 * 5 * 8 * 4);
    if (off > ws_size) return;

    build_ell<<<256, 256, 0, stream>>>(supports, ell8, ell4, ecnt);
    {
        int nz = RTOT * UU * 2 + RTOT;  // h0a, h1a, xzero contiguous
        zero_kernel<<<(nz + 255) / 256, 256, 0, stream>>>(h0a, nz);
    }
    wprep<<<(5 * 64 * 128 + 255) / 256, 256, 0, stream>>>(enc0_Wg, p_e0g, x_e0g, 64, 128, 8, 1);
    wprep<<<(5 * 64 * 64 + 255) / 256, 256, 0, stream>>>(enc0_Wc, p_e0c, x_e0c, 64, 64, 4, 1);
    wprep<<<(5 * 128 * 128 + 255) / 256, 256, 0, stream>>>(enc1_Wg, p_e1g, xdum, 128, 128, 8, 0);
    wprep<<<(5 * 128 * 64 + 255) / 256, 256, 0, stream>>>(enc1_Wc, p_e1c, xdum, 128, 64, 4, 0);
    wprep<<<(5 * 64 * 128 + 255) / 256, 256, 0, stream>>>(dec0_Wg, p_d0g, x_d0g, 64, 128, 8, 1);
    wprep<<<(5 * 64 * 64 + 255) / 256, 256, 0, stream>>>(dec0_Wc, p_d0c, x_d0c, 64, 64, 4, 1);
    wprep<<<(5 * 128 * 128 + 255) / 256, 256, 0, stream>>>(dec1_Wg, p_d1g, xdum, 128, 128, 8, 0);
    wprep<<<(5 * 128 * 64 + 255) / 256, 256, 0, stream>>>(dec1_Wc, p_d1c, xdum, 128, 64, 4, 0);

    float *h0c = h0a, *h0n = h0b, *h1c = h1a, *h1n = h1b;

    auto cell_l0 = [&](const float* x_bn, const float* Wg_, const float* Xg_,
                       const float* bg_, const float* Wc_, const float* Xc_,
                       const float* bc_) {
        fused<true, true><<<512, 512, 0, stream>>>(h0c, nullptr, g, Wg_, Xg_, x_bn,
                                                   bg_, ell8, ecnt, g, nullptr, nullptr);
        fused<true, false><<<512, 512, 0, stream>>>(h0c, nullptr, g, Wc_, Xc_, x_bn,
                                                    bc_, ell4, ecnt, nullptr, h0c, h0n);
        float* t = h0c; h0c = h0n; h0n = t;
    };
    auto cell_l1 = [&](const float* Wg_, const float* bg_,
                       const float* Wc_, const float* bc_) {
        fused<false, true><<<512, 512, 0, stream>>>(h0c, h1c, g, Wg_, nullptr, nullptr,
                                                    bg_, ell8, ecnt, g, nullptr, nullptr);
        fused<false, false><<<512, 512, 0, stream>>>(h0c, h1c, g, Wc_, nullptr, nullptr,
                                                     bc_, ell4, ecnt, nullptr, h1c, h1n);
        float* t = h1c; h1c = h1n; h1n = t;
    };

    for (int t = 0; t < TT; ++t) {
        cell_l0(inputs + (size_t)t * BB * NN, p_e0g, x_e0g, enc0_bg, p_e0c, x_e0c, enc0_bc);
        cell_l1(p_e1g, enc1_bg, p_e1c, enc1_bc);
    }
    for (int t = 0; t < HH; ++t) {
        const float* xin = (t == 0) ? xzero : (out + (size_t)(t - 1) * BB * NN);
        cell_l0(xin, p_d0g, x_d0g, dec0_bg, p_d0c, x_d0c, dec0_bc);
        cell_l1(p_d1g, dec1_bg, p_d1c, dec1_bc);
        proj_kernel<<<(RTOT + 255) / 256, 256, 0, stream>>>(h1c, projW, projb,
                                                            out + (size_t)t * BB * NN);
    }
}